// Round 1
// baseline (552.237 us; speedup 1.0000x reference)
//
#include <hip/hip_runtime.h>

#define BB 8
#define CC_ALL 128
#define HH 160
#define WW 160
#define PAD 4
#define RANGE 9
#define ND 80           // 81 - center
#define TW 32           // tile width (px)
#define TH 16           // tile height (px)
#define PXT 2           // px per thread along w
#define NTX (TW / PXT)  // 16
#define NTY TH          // 16
#define CCHUNK 8        // channels staged per LDS chunk
#define HALO_W (TW + 2 * PAD)  // 40
#define HALO_H (TH + 2 * PAD)  // 24
#define PLANE (HH * WW)        // 25600

__global__ __launch_bounds__(256, 2)
void cost_volume_kernel(const float* __restrict__ f1,
                        const float* __restrict__ f2,
                        float* __restrict__ out) {
    __shared__ __align__(16) float s2[CCHUNK][HALO_H][HALO_W];

    const int tile_x = blockIdx.x;          // 0..4
    const int tile_y = blockIdx.y;          // 0..9
    const int b      = blockIdx.z;          // 0..7
    const int w0 = tile_x * TW;
    const int h0 = tile_y * TH;
    const int tid = threadIdx.x;
    const int tx = tid & (NTX - 1);         // 0..15
    const int ty = tid >> 4;                // 0..15
    const int w = w0 + tx * PXT;            // even
    const int h = h0 + ty;

    float acc[ND * PXT];
#pragma unroll
    for (int i = 0; i < ND * PXT; i++) acc[i] = 0.f;

    const float* f1base = f1 + (size_t)b * CC_ALL * PLANE + (size_t)h * WW + w;
    const float* f2base = f2 + (size_t)b * CC_ALL * PLANE;

    for (int c0 = 0; c0 < CC_ALL; c0 += CCHUNK) {
        // ---- stage CCHUNK channels of feat2 halo into LDS (zero-padded) ----
        // total elems: 8*24*40 = 7680 = 256 * 30
        for (int idx = tid; idx < CCHUNK * HALO_H * HALO_W; idx += 256) {
            const int cw = idx % HALO_W;
            const int t  = idx / HALO_W;
            const int rr = t % HALO_H;
            const int cc = t / HALO_H;
            const int gw = w0 - PAD + cw;
            const int gh = h0 - PAD + rr;
            float v = 0.f;
            if ((unsigned)gw < WW && (unsigned)gh < HH)
                v = f2base[(size_t)(c0 + cc) * PLANE + (size_t)gh * WW + gw];
            s2[cc][rr][cw] = v;
        }
        __syncthreads();

#pragma unroll
        for (int cc = 0; cc < CCHUNK; cc++) {
            const float2 f1v = *(const float2*)(f1base + (size_t)(c0 + cc) * PLANE);
#pragma unroll
            for (int di = 0; di < RANGE; di++) {
                const float* rowp = &s2[cc][ty + di][tx * PXT];
                float win[PXT + RANGE - 1 + 1];  // 10 floats: w-4 .. w+5
#pragma unroll
                for (int k = 0; k < 5; k++) {
                    const float2 t2 = *(const float2*)(rowp + 2 * k);
                    win[2 * k]     = t2.x;
                    win[2 * k + 1] = t2.y;
                }
#pragma unroll
                for (int dj = 0; dj < RANGE; dj++) {
                    if (di == PAD && dj == PAD) continue;
                    const int lin = di * RANGE + dj;
                    const int d = (lin < 40) ? lin : (lin - 1);
                    acc[d * 2 + 0] += f1v.x * win[dj];
                    acc[d * 2 + 1] += f1v.y * win[dj + 1];
                }
            }
        }
        __syncthreads();
    }

    // ---- epilogue: mean (x 1/128) and store ----
    float* outp = out + (size_t)b * ND * PLANE + (size_t)h * WW + w;
#pragma unroll
    for (int d = 0; d < ND; d++) {
        float2 o;
        o.x = acc[2 * d + 0] * (1.f / 128.f);
        o.y = acc[2 * d + 1] * (1.f / 128.f);
        *(float2*)(outp + (size_t)d * PLANE) = o;
    }
}

extern "C" void kernel_launch(void* const* d_in, const int* in_sizes, int n_in,
                              void* d_out, int out_size, void* d_ws, size_t ws_size,
                              hipStream_t stream) {
    const float* feat1 = (const float*)d_in[0];
    const float* feat2 = (const float*)d_in[1];
    float* out = (float*)d_out;

    dim3 grid(WW / TW, HH / TH, BB);   // 5 x 10 x 8 = 400 blocks
    dim3 block(256);
    cost_volume_kernel<<<grid, block, 0, stream>>>(feat1, feat2, out);
}